// Round 10
// baseline (65.090 us; speedup 1.0000x reference)
//
#include <hip/hip_runtime.h>
#include <stdint.h>
#include <math.h>

#define NN 8192
#define DD 128
#define NB 64                    // 8192/128 tiles per dim
#define NBLK (NB * (NB + 1) / 2) // 2080 upper-triangular tile blocks
#define NC 32                    // classes
#define NPB 256                  // prep blocks (= class partial blocks)
#define RPB 32                   // rows per prep block
#define TOTBLK (NBLK + NC)       // fused loss grid
#define SCALE (2.0f / ((float)NN * (float)(NN - 1)))

typedef __attribute__((ext_vector_type(4))) float f32x4;

// fp8 e4m3 fragment-major layout (for mfma_f32_16x16x32_fp8_fp8):
// panel = row>>4; byte(row,k) = panel*2048 + (k>>5)*512 + ((k>>3)&3)*128 + (row&15)*8 + (k&7)
// -> wave-load for (panel, ks): lane l reads 8B at panel*2048 + ks*512 + (l>>4)*128 + (l&15)*8

__device__ __forceinline__ uint32_t pk4_fp8(float f0, float f1, float f2, float f3) {
    int d = __builtin_amdgcn_cvt_pk_fp8_f32(f0, f1, 0, false);   // bytes 0,1
    d = __builtin_amdgcn_cvt_pk_fp8_f32(f2, f3, d, true);        // bytes 2,3
    return (uint32_t)d;
}

// prep: identical to R8.
__global__ __launch_bounds__(256) void prep_kernel(const float* __restrict__ ys,
                                                   const int* __restrict__ lab,
                                                   uint32_t* __restrict__ a8,
                                                   uint32_t* __restrict__ b8,
                                                   float* __restrict__ sq,
                                                   float* __restrict__ clspart,
                                                   float* __restrict__ out) {
    int b = blockIdx.x, t = threadIdx.x;
    __shared__ float cls[4][NC][DD];   // 64 KB
    __shared__ int slab[RPB];

#pragma unroll
    for (int i = 0; i < 16; ++i) ((float4*)cls)[i * 256 + t] = make_float4(0.f, 0.f, 0.f, 0.f);
    if (t < RPB) slab[t] = lab[b * RPB + t];

#pragma unroll
    for (int u = 0; u < 2; ++u) {
        int rloc = (t >> 4) + u * 16;   // 0..31
        int c8 = t & 15;                // 8-float chunk within row (k = c8*8)
        int row = b * RPB + rloc;
        const float* base = ys + (size_t)row * DD + c8 * 8;
        float4 v0 = *(const float4*)base;
        float4 v1 = *(const float4*)(base + 4);
        uint2 outB = make_uint2(pk4_fp8(v0.x, v0.y, v0.z, v0.w),
                                pk4_fp8(v1.x, v1.y, v1.z, v1.w));
        uint2 outA = make_uint2(pk4_fp8(-2.f * v0.x, -2.f * v0.y, -2.f * v0.z, -2.f * v0.w),
                                pk4_fp8(-2.f * v1.x, -2.f * v1.y, -2.f * v1.z, -2.f * v1.w));
        size_t off = (size_t)(b * 2 + u) * 2048 + (c8 >> 2) * 512 + (c8 & 3) * 128 + (rloc & 15) * 8;
        *(uint2*)((char*)b8 + off) = outB;
        *(uint2*)((char*)a8 + off) = outA;
        float s = v0.x * v0.x + v0.y * v0.y + v0.z * v0.z + v0.w * v0.w
                + v1.x * v1.x + v1.y * v1.y + v1.z * v1.z + v1.w * v1.w;
        s += __shfl_xor(s, 1); s += __shfl_xor(s, 2);
        s += __shfl_xor(s, 4); s += __shfl_xor(s, 8);
        if (c8 == 0) sq[row] = s;
    }
    __syncthreads();

    {
        int g = t >> 6, col0 = (t & 63) * 2;
#pragma unroll
        for (int rr = 0; rr < 8; ++rr) {
            int rloc = g * 8 + rr;
            float2 v = *(const float2*)(ys + (size_t)(b * RPB + rloc) * DD + col0);
            int lb = slab[rloc];
            cls[g][lb][col0]     += v.x;
            cls[g][lb][col0 + 1] += v.y;
        }
    }
    __syncthreads();
#pragma unroll
    for (int i = 0; i < 4; ++i) {
        int idx = i * 256 + t;
        float4 s0 = ((const float4*)cls[0])[idx];
        float4 s1 = ((const float4*)cls[1])[idx];
        float4 s2 = ((const float4*)cls[2])[idx];
        float4 s3 = ((const float4*)cls[3])[idx];
        ((float4*)(clspart + (size_t)b * NC * DD))[idx] =
            make_float4((s0.x + s1.x) + (s2.x + s3.x), (s0.y + s1.y) + (s2.y + s3.y),
                        (s0.z + s1.z) + (s2.z + s3.z), (s0.w + s1.w) + (s2.w + s3.w));
    }
    if (b == 0 && t == 0) out[0] = 0.f;
}

// Fused loss: R8 + ATTRIBUTION PROBE (4 junk k-loop passes, kept live via asm,
// acc re-zeroed before the real pass — output identical to R8).
__global__ __launch_bounds__(256) void loss_kernel(const uint32_t* __restrict__ a8,
                                                   const uint32_t* __restrict__ b8,
                                                   const float* __restrict__ sq,
                                                   const int* __restrict__ lab,
                                                   const float* __restrict__ clspart,
                                                   const float* __restrict__ ys,
                                                   float* __restrict__ out) {
    int p = blockIdx.x, t = threadIdx.x;

    if (p < NC) {
        // ---- classred for class p (identical to R8) ----
        __shared__ float sp[2][DD];
        __shared__ float redc[4], reds[4], red2[2];
        int col = t & 127, half = t >> 7;
        float S0 = 0.f, S1 = 0.f, S2 = 0.f, S3 = 0.f;
        const float* cp = clspart + (size_t)half * 128 * NC * DD + p * DD + col;
#pragma unroll 8
        for (int pb = 0; pb < 128; pb += 4) {
            S0 += cp[(size_t)(pb + 0) * NC * DD];
            S1 += cp[(size_t)(pb + 1) * NC * DD];
            S2 += cp[(size_t)(pb + 2) * NC * DD];
            S3 += cp[(size_t)(pb + 3) * NC * DD];
        }
        sp[half][col] = (S0 + S1) + (S2 + S3);

        float cnt = 0.f, ssq = 0.f;
        for (int rr = t; rr < NN; rr += 256) {
            if (lab[rr] == p) { cnt += 1.f; ssq += sq[rr]; }
        }
#pragma unroll
        for (int off = 32; off >= 1; off >>= 1) {
            cnt += __shfl_down(cnt, off);
            ssq += __shfl_down(ssq, off);
        }
        if ((t & 63) == 0) { redc[t >> 6] = cnt; reds[t >> 6] = ssq; }
        __syncthreads();

        float s2 = 0.f;
        if (t < DD) { float Sc = sp[0][t] + sp[1][t]; s2 = Sc * Sc; }
#pragma unroll
        for (int off = 32; off >= 1; off >>= 1) s2 += __shfl_down(s2, off);
        if (t < 128 && (t & 63) == 0) red2[t >> 6] = s2;
        __syncthreads();
        if (t == 0) {
            float c = redc[0] + redc[1] + redc[2] + redc[3];
            float s = reds[0] + reds[1] + reds[2] + reds[3];
            atomicAdd(out, (c * s - (red2[0] + red2[1])) * SCALE);
        }
        return;
    }

    // ---- tile GEMM ----
    int pt = p - NC;
    int q = (NBLK - 1) - pt;
    int r = (int)((sqrtf(8.0f * (float)q + 1.0f) - 1.0f) * 0.5f);
    while (r * (r + 1) / 2 > q) --r;
    while ((r + 1) * (r + 2) / 2 <= q) ++r;
    int bi = (NB - 1) - r;
    int bj = (NB - 1) - (q - r * (r + 1) / 2);
    int i0 = bi * 128, j0 = bj * 128;

    int wave = t >> 6, lane = t & 63;
    int wm = wave >> 1, wn = wave & 1;
    int lr = lane & 15, lg = lane >> 4;

    f32x4 acc[4][4];
#pragma unroll
    for (int m = 0; m < 4; ++m)
#pragma unroll
        for (int n = 0; n < 4; ++n) acc[m][n] = (f32x4){0.f, 0.f, 0.f, 0.f};

    int lo = lg * 128 + lr * 8;   // lane offset within a (panel, ks) 512B slab

    // ===== ATTRIBUTION PROBE: 4 junk passes, same inst mix, distinct L2 lines =====
#pragma unroll 1
    for (int rep = 1; rep <= 4; ++rep) {
        int po = rep * 64;   // panel offset (wraps via &511, stays in-bounds)
#pragma unroll
        for (int ks = 0; ks < 4; ++ks) {
            long af[4], bf[4];
#pragma unroll
            for (int m = 0; m < 4; ++m) {
                int pan = ((i0 >> 4) + wm * 4 + m + po) & 511;
                af[m] = *(const long*)((const char*)a8 + (size_t)pan * 2048 + ks * 512 + lo);
            }
#pragma unroll
            for (int n = 0; n < 4; ++n) {
                int pan = ((j0 >> 4) + wn * 4 + n + po) & 511;
                bf[n] = *(const long*)((const char*)b8 + (size_t)pan * 2048 + ks * 512 + lo);
            }
#pragma unroll
            for (int m = 0; m < 4; ++m)
#pragma unroll
                for (int n = 0; n < 4; ++n)
                    acc[m][n] = __builtin_amdgcn_mfma_f32_16x16x32_fp8_fp8(af[m], bf[n], acc[m][n], 0, 0, 0);
        }
    }
    // keep junk results live (no DCE), then reset accumulators
#pragma unroll
    for (int m = 0; m < 4; ++m)
#pragma unroll
        for (int n = 0; n < 4; ++n) {
            asm volatile("" :: "v"(acc[m][n][0]), "v"(acc[m][n][1]),
                              "v"(acc[m][n][2]), "v"(acc[m][n][3]));
            acc[m][n] = (f32x4){0.f, 0.f, 0.f, 0.f};
        }
    // ===== end probe =====

    const char* pa = (const char*)a8 + ((size_t)(i0 >> 4) + wm * 4) * 2048 + lo;
    const char* pbp = (const char*)b8 + ((size_t)(j0 >> 4) + wn * 4) * 2048 + lo;

#pragma unroll
    for (int ks = 0; ks < 4; ++ks) {
        long af[4], bf[4];
#pragma unroll
        for (int m = 0; m < 4; ++m) af[m] = *(const long*)(pa + m * 2048 + ks * 512);
#pragma unroll
        for (int n = 0; n < 4; ++n) bf[n] = *(const long*)(pbp + n * 2048 + ks * 512);
#pragma unroll
        for (int m = 0; m < 4; ++m)
#pragma unroll
            for (int n = 0; n < 4; ++n)
                acc[m][n] = __builtin_amdgcn_mfma_f32_16x16x32_fp8_fp8(af[m], bf[n], acc[m][n], 0, 0, 0);
    }

    // acc[m][n][q] == -2*dot_fp8(i,j); d2 = acc + sq_i + sq_j.
    float msi = fminf(sq[i0 + lane * 2], sq[i0 + lane * 2 + 1]);
    float msj = fminf(sq[j0 + lane * 2], sq[j0 + lane * 2 + 1]);
#pragma unroll
    for (int off = 32; off >= 1; off >>= 1) {
        msi = fminf(msi, __shfl_xor(msi, off));
        msj = fminf(msj, __shfl_xor(msj, off));
    }
    float mn = acc[0][0][0];
#pragma unroll
    for (int m = 0; m < 4; ++m)
#pragma unroll
        for (int n = 0; n < 4; ++n)
#pragma unroll
            for (int qq = 0; qq < 4; ++qq) mn = fminf(mn, acc[m][n][qq]);

    if (__any(mn + msi + msj < 20.0f)) {
        // Slow path (never taken for this data): exact re-verification from ys.
        float ns = 0.f;
#pragma unroll
        for (int m = 0; m < 4; ++m)
#pragma unroll
            for (int n = 0; n < 4; ++n)
#pragma unroll
                for (int qq = 0; qq < 4; ++qq) {
                    int i = i0 + wm * 64 + m * 16 + lg * 4 + qq;
                    int j = j0 + wn * 64 + n * 16 + lr;
                    float d2a = acc[m][n][qq] + sq[i] + sq[j];
                    if (d2a < 20.0f && i < j && lab[i] != lab[j]) {
                        float d2e = 0.f;
                        for (int d = 0; d < DD; ++d) {
                            float df = ys[(size_t)i * DD + d] - ys[(size_t)j * DD + d];
                            d2e += df * df;
                        }
                        if (d2e < 1.0f) { float e = 1.0f - sqrtf(d2e); ns += e * e; }
                    }
                }
        if (ns != 0.f) atomicAdd(out, ns * SCALE);
    }
}

extern "C" void kernel_launch(void* const* d_in, const int* in_sizes, int n_in,
                              void* d_out, int out_size, void* d_ws, size_t ws_size,
                              hipStream_t stream) {
    const float* ys = (const float*)d_in[0];
    const int* lab = (const int*)d_in[1];
    float* out = (float*)d_out;

    char* w = (char*)d_ws;
    uint32_t* a8    = (uint32_t*)(w);                 // 1 MB (-2y fp8, frag-major)
    uint32_t* b8    = (uint32_t*)(w + 1048576);       // 1 MB (y fp8)
    float* sq       = (float*)(w + 2097152);          // 32 KB
    float* clspart  = (float*)(w + 2129920);          // 4 MB

    prep_kernel<<<NPB, 256, 0, stream>>>(ys, lab, a8, b8, sq, clspart, out);
    loss_kernel<<<TOTBLK, 256, 0, stream>>>(a8, b8, sq, lab, clspart, ys, out);
}

// Round 11
// 52.619 us; speedup vs baseline: 1.2370x; 1.2370x over previous
//
#include <hip/hip_runtime.h>
#include <stdint.h>
#include <math.h>

#define NN 8192
#define DD 128
#define NB 64                    // 8192/128 tiles per dim
#define NBLK (NB * (NB + 1) / 2) // 2080 upper-triangular tile blocks
#define NC 32                    // classes
#define NPB 256                  // prep blocks (= class partial blocks)
#define RPB 32                   // rows per prep block
#define NTB (NBLK / 4)           // 520 tile blocks, 4 tiles each
#define TOTBLK (NTB + NC)        // fused loss grid: 552
#define SCALE (2.0f / ((float)NN * (float)(NN - 1)))

typedef __attribute__((ext_vector_type(4))) float f32x4;

// fp8 e4m3 fragment-major layout (for mfma_f32_16x16x32_fp8_fp8):
// panel = row>>4; byte(row,k) = panel*2048 + (k>>5)*512 + ((k>>3)&3)*128 + (row&15)*8 + (k&7)

__device__ __forceinline__ uint32_t pk4_fp8(float f0, float f1, float f2, float f3) {
    int d = __builtin_amdgcn_cvt_pk_fp8_f32(f0, f1, 0, false);   // bytes 0,1
    d = __builtin_amdgcn_cvt_pk_fp8_f32(f2, f3, d, true);        // bytes 2,3
    return (uint32_t)d;
}

// prep: identical to R8 (validated).
__global__ __launch_bounds__(256) void prep_kernel(const float* __restrict__ ys,
                                                   const int* __restrict__ lab,
                                                   uint32_t* __restrict__ a8,
                                                   uint32_t* __restrict__ b8,
                                                   float* __restrict__ sq,
                                                   float* __restrict__ clspart,
                                                   float* __restrict__ out) {
    int b = blockIdx.x, t = threadIdx.x;
    __shared__ float cls[4][NC][DD];   // 64 KB
    __shared__ int slab[RPB];

#pragma unroll
    for (int i = 0; i < 16; ++i) ((float4*)cls)[i * 256 + t] = make_float4(0.f, 0.f, 0.f, 0.f);
    if (t < RPB) slab[t] = lab[b * RPB + t];

#pragma unroll
    for (int u = 0; u < 2; ++u) {
        int rloc = (t >> 4) + u * 16;   // 0..31
        int c8 = t & 15;                // 8-float chunk within row (k = c8*8)
        int row = b * RPB + rloc;
        const float* base = ys + (size_t)row * DD + c8 * 8;
        float4 v0 = *(const float4*)base;
        float4 v1 = *(const float4*)(base + 4);
        uint2 outB = make_uint2(pk4_fp8(v0.x, v0.y, v0.z, v0.w),
                                pk4_fp8(v1.x, v1.y, v1.z, v1.w));
        uint2 outA = make_uint2(pk4_fp8(-2.f * v0.x, -2.f * v0.y, -2.f * v0.z, -2.f * v0.w),
                                pk4_fp8(-2.f * v1.x, -2.f * v1.y, -2.f * v1.z, -2.f * v1.w));
        size_t off = (size_t)(b * 2 + u) * 2048 + (c8 >> 2) * 512 + (c8 & 3) * 128 + (rloc & 15) * 8;
        *(uint2*)((char*)b8 + off) = outB;
        *(uint2*)((char*)a8 + off) = outA;
        float s = v0.x * v0.x + v0.y * v0.y + v0.z * v0.z + v0.w * v0.w
                + v1.x * v1.x + v1.y * v1.y + v1.z * v1.z + v1.w * v1.w;
        s += __shfl_xor(s, 1); s += __shfl_xor(s, 2);
        s += __shfl_xor(s, 4); s += __shfl_xor(s, 8);
        if (c8 == 0) sq[row] = s;
    }
    __syncthreads();

    {
        int g = t >> 6, col0 = (t & 63) * 2;
#pragma unroll
        for (int rr = 0; rr < 8; ++rr) {
            int rloc = g * 8 + rr;
            float2 v = *(const float2*)(ys + (size_t)(b * RPB + rloc) * DD + col0);
            int lb = slab[rloc];
            cls[g][lb][col0]     += v.x;
            cls[g][lb][col0 + 1] += v.y;
        }
    }
    __syncthreads();
#pragma unroll
    for (int i = 0; i < 4; ++i) {
        int idx = i * 256 + t;
        float4 s0 = ((const float4*)cls[0])[idx];
        float4 s1 = ((const float4*)cls[1])[idx];
        float4 s2 = ((const float4*)cls[2])[idx];
        float4 s3 = ((const float4*)cls[3])[idx];
        ((float4*)(clspart + (size_t)b * NC * DD))[idx] =
            make_float4((s0.x + s1.x) + (s2.x + s3.x), (s0.y + s1.y) + (s2.y + s3.y),
                        (s0.z + s1.z) + (s2.z + s3.z), (s0.w + s1.w) + (s2.w + s3.w));
    }
    if (b == 0 && t == 0) out[0] = 0.f;
}

#define LD_HALF(Abuf, Bbuf, pA_, pB_, h)                                          \
    {                                                                             \
        _Pragma("unroll") for (int kk = 0; kk < 2; ++kk)                          \
            _Pragma("unroll") for (int m = 0; m < 4; ++m) {                       \
                Abuf[kk][m] = *(const long*)((pA_) + m * 2048 + (2 * (h) + kk) * 512); \
                Bbuf[kk][m] = *(const long*)((pB_) + m * 2048 + (2 * (h) + kk) * 512); \
            }                                                                     \
    }

#define MF_HALF(Abuf, Bbuf)                                                       \
    {                                                                             \
        _Pragma("unroll") for (int kk = 0; kk < 2; ++kk)                          \
            _Pragma("unroll") for (int m = 0; m < 4; ++m)                         \
                _Pragma("unroll") for (int n = 0; n < 4; ++n)                     \
                    acc[m][n] = __builtin_amdgcn_mfma_f32_16x16x32_fp8_fp8(       \
                        Abuf[kk][m], Bbuf[kk][n], acc[m][n], 0, 0, 0);            \
    }

// Fused loss: blocks 0..31 = classred; blocks 32..551 = 4 consecutive tiles each,
// software-pipelined at half-tile granularity (16 loads always in flight).
__global__ __launch_bounds__(256, 3) void loss_kernel(const uint32_t* __restrict__ a8,
                                                      const uint32_t* __restrict__ b8,
                                                      const float* __restrict__ sq,
                                                      const int* __restrict__ lab,
                                                      const float* __restrict__ clspart,
                                                      const float* __restrict__ ys,
                                                      float* __restrict__ out) {
    int p = blockIdx.x, t = threadIdx.x;

    if (p < NC) {
        // ---- classred for class p, ILP-8 ----
        __shared__ float sp[2][DD];
        __shared__ float redc[4], reds[4], red2[2];
        int col = t & 127, half = t >> 7;
        const float* cp = clspart + (size_t)half * 128 * NC * DD + p * DD + col;
        float S[8] = {0.f, 0.f, 0.f, 0.f, 0.f, 0.f, 0.f, 0.f};
#pragma unroll 2
        for (int pb = 0; pb < 128; pb += 8) {
#pragma unroll
            for (int u = 0; u < 8; ++u) S[u] += cp[(size_t)(pb + u) * NC * DD];
        }
        sp[half][col] = ((S[0] + S[1]) + (S[2] + S[3])) + ((S[4] + S[5]) + (S[6] + S[7]));

        float cnt = 0.f, ssq = 0.f;
#pragma unroll 4
        for (int rr = t; rr < NN; rr += 256) {
            if (lab[rr] == p) { cnt += 1.f; ssq += sq[rr]; }
        }
#pragma unroll
        for (int off = 32; off >= 1; off >>= 1) {
            cnt += __shfl_down(cnt, off);
            ssq += __shfl_down(ssq, off);
        }
        if ((t & 63) == 0) { redc[t >> 6] = cnt; reds[t >> 6] = ssq; }
        __syncthreads();

        float s2 = 0.f;
        if (t < DD) { float Sc = sp[0][t] + sp[1][t]; s2 = Sc * Sc; }
#pragma unroll
        for (int off = 32; off >= 1; off >>= 1) s2 += __shfl_down(s2, off);
        if (t < 128 && (t & 63) == 0) red2[t >> 6] = s2;
        __syncthreads();
        if (t == 0) {
            float c = redc[0] + redc[1] + redc[2] + redc[3];
            float s = reds[0] + reds[1] + reds[2] + reds[3];
            atomicAdd(out, (c * s - (red2[0] + red2[1])) * SCALE);
        }
        return;
    }

    // ---- 4-tile pipelined GEMM ----
    int pt0 = (p - NC) * 4;
    // Triangular decode of pt0 (row-major: (0,0),(0,1)..(0,63),(1,1)..): then increment.
    int q = (NBLK - 1) - pt0;
    int r = (int)((sqrtf(8.0f * (float)q + 1.0f) - 1.0f) * 0.5f);
    while (r * (r + 1) / 2 > q) --r;
    while ((r + 1) * (r + 2) / 2 <= q) ++r;
    int bi = (NB - 1) - r;
    int bj = (NB - 1) - (q - r * (r + 1) / 2);

    int wave = t >> 6, lane = t & 63;
    int wm = wave >> 1, wn = wave & 1;
    int lr = lane & 15, lg = lane >> 4;
    int lo = lg * 128 + lr * 8;   // lane offset within a (panel, ks) 512B slab

    // Hoist per-tile bases, i0/j0, and sq-min bounds BEFORE the pipeline
    // (so the epilogue never drains vmcnt on fragment loads).
    const char* pA[4]; const char* pB[4];
    int i0s[4], j0s[4];
    float msum[4];
    {
        int cbi = bi, cbj = bj;
#pragma unroll
        for (int tt = 0; tt < 4; ++tt) {
            pA[tt] = (const char*)a8 + ((size_t)cbi * 8 + wm * 4) * 2048 + lo;
            pB[tt] = (const char*)b8 + ((size_t)cbj * 8 + wn * 4) * 2048 + lo;
            int i0 = cbi * 128, j0 = cbj * 128;
            i0s[tt] = i0; j0s[tt] = j0;
            float a = fminf(sq[i0 + lane * 2], sq[i0 + lane * 2 + 1]);
            float b2 = fminf(sq[j0 + lane * 2], sq[j0 + lane * 2 + 1]);
#pragma unroll
            for (int off = 32; off >= 1; off >>= 1) {
                a = fminf(a, __shfl_xor(a, off));
                b2 = fminf(b2, __shfl_xor(b2, off));
            }
            msum[tt] = a + b2;
            ++cbj; if (cbj == NB) { ++cbi; cbj = cbi; }
        }
    }

    f32x4 acc[4][4];
#pragma unroll
    for (int m = 0; m < 4; ++m)
#pragma unroll
        for (int n = 0; n < 4; ++n) acc[m][n] = (f32x4){0.f, 0.f, 0.f, 0.f};

    long A0[2][4], B0[2][4], A1[2][4], B1[2][4];
    LD_HALF(A0, B0, pA[0], pB[0], 0)
    LD_HALF(A1, B1, pA[0], pB[0], 1)

    float total_ns = 0.f;
#pragma unroll
    for (int tt = 0; tt < 4; ++tt) {
        MF_HALF(A0, B0)
        if (tt < 3) LD_HALF(A0, B0, pA[tt + 1], pB[tt + 1], 0)
        MF_HALF(A1, B1)
        if (tt < 3) LD_HALF(A1, B1, pA[tt + 1], pB[tt + 1], 1)

        // Epilogue tile tt: acc == -2*dot_fp8; d2 = acc + sq_i + sq_j.
        float mn = acc[0][0][0];
#pragma unroll
        for (int m = 0; m < 4; ++m)
#pragma unroll
            for (int n = 0; n < 4; ++n)
#pragma unroll
                for (int qq = 0; qq < 4; ++qq) mn = fminf(mn, acc[m][n][qq]);

        if (__any(mn + msum[tt] < 20.0f)) {
            // Slow path (never taken off-diagonal; diagonal short-circuits on i<j).
#pragma unroll
            for (int m = 0; m < 4; ++m)
#pragma unroll
                for (int n = 0; n < 4; ++n)
#pragma unroll
                    for (int qq = 0; qq < 4; ++qq) {
                        int i = i0s[tt] + wm * 64 + m * 16 + lg * 4 + qq;
                        int j = j0s[tt] + wn * 64 + n * 16 + lr;
                        if (i < j) {
                            float d2a = acc[m][n][qq] + sq[i] + sq[j];
                            if (d2a < 20.0f && lab[i] != lab[j]) {
                                float d2e = 0.f;
                                for (int d = 0; d < DD; ++d) {
                                    float df = ys[(size_t)i * DD + d] - ys[(size_t)j * DD + d];
                                    d2e += df * df;
                                }
                                if (d2e < 1.0f) { float e = 1.0f - sqrtf(d2e); total_ns += e * e; }
                            }
                        }
                    }
        }
#pragma unroll
        for (int m = 0; m < 4; ++m)
#pragma unroll
            for (int n = 0; n < 4; ++n) acc[m][n] = (f32x4){0.f, 0.f, 0.f, 0.f};
    }
    if (total_ns != 0.f) atomicAdd(out, total_ns * SCALE);
}

extern "C" void kernel_launch(void* const* d_in, const int* in_sizes, int n_in,
                              void* d_out, int out_size, void* d_ws, size_t ws_size,
                              hipStream_t stream) {
    const float* ys = (const float*)d_in[0];
    const int* lab = (const int*)d_in[1];
    float* out = (float*)d_out;

    char* w = (char*)d_ws;
    uint32_t* a8    = (uint32_t*)(w);                 // 1 MB (-2y fp8, frag-major)
    uint32_t* b8    = (uint32_t*)(w + 1048576);       // 1 MB (y fp8)
    float* sq       = (float*)(w + 2097152);          // 32 KB
    float* clspart  = (float*)(w + 2129920);          // 4 MB

    prep_kernel<<<NPB, 256, 0, stream>>>(ys, lab, a8, b8, sq, clspart, out);
    loss_kernel<<<TOTBLK, 256, 0, stream>>>(a8, b8, sq, lab, clspart, ys, out);
}

// Round 12
// 40.920 us; speedup vs baseline: 1.5907x; 1.2859x over previous
//
#include <hip/hip_runtime.h>
#include <stdint.h>
#include <math.h>

#define NN 8192
#define DD 128
#define NB 64                    // 8192/128 tiles per dim
#define NBLK (NB * (NB + 1) / 2) // 2080 upper-triangular tile blocks
#define NC 32                    // classes
#define NPB 256                  // prep blocks (= class partial blocks)
#define RPB 32                   // rows per prep block
#define NTB (NBLK / 2)           // 1040 tile blocks, 2 tiles each
#define SCALE (2.0f / ((float)NN * (float)(NN - 1)))

typedef __attribute__((ext_vector_type(4))) float f32x4;

// fp8 e4m3 fragment-major layout (for mfma_f32_16x16x32_fp8_fp8):
// panel = row>>4; byte(row,k) = panel*2048 + (k>>5)*512 + ((k>>3)&3)*128 + (row&15)*8 + (k&7)

__device__ __forceinline__ uint32_t pk4_fp8(float f0, float f1, float f2, float f3) {
    int d = __builtin_amdgcn_cvt_pk_fp8_f32(f0, f1, 0, false);   // bytes 0,1
    d = __builtin_amdgcn_cvt_pk_fp8_f32(f2, f3, d, true);        // bytes 2,3
    return (uint32_t)d;
}

// prep: R8-validated + tminpart[b] (min sq over the block's 32 rows).
__global__ __launch_bounds__(256) void prep_kernel(const float* __restrict__ ys,
                                                   const int* __restrict__ lab,
                                                   uint32_t* __restrict__ a8,
                                                   uint32_t* __restrict__ b8,
                                                   float* __restrict__ sq,
                                                   float* __restrict__ clspart,
                                                   float* __restrict__ tminpart,
                                                   float* __restrict__ out) {
    int b = blockIdx.x, t = threadIdx.x;
    __shared__ float cls[4][NC][DD];   // 64 KB
    __shared__ int slab[RPB];
    __shared__ int tmn;

#pragma unroll
    for (int i = 0; i < 16; ++i) ((float4*)cls)[i * 256 + t] = make_float4(0.f, 0.f, 0.f, 0.f);
    if (t < RPB) slab[t] = lab[b * RPB + t];
    if (t == 0) tmn = 0x7f800000;   // +inf bits (sq > 0, int cmp == float cmp)

    float myMin = 1e30f;
#pragma unroll
    for (int u = 0; u < 2; ++u) {
        int rloc = (t >> 4) + u * 16;   // 0..31
        int c8 = t & 15;                // 8-float chunk within row (k = c8*8)
        int row = b * RPB + rloc;
        const float* base = ys + (size_t)row * DD + c8 * 8;
        float4 v0 = *(const float4*)base;
        float4 v1 = *(const float4*)(base + 4);
        uint2 outB = make_uint2(pk4_fp8(v0.x, v0.y, v0.z, v0.w),
                                pk4_fp8(v1.x, v1.y, v1.z, v1.w));
        uint2 outA = make_uint2(pk4_fp8(-2.f * v0.x, -2.f * v0.y, -2.f * v0.z, -2.f * v0.w),
                                pk4_fp8(-2.f * v1.x, -2.f * v1.y, -2.f * v1.z, -2.f * v1.w));
        size_t off = (size_t)(b * 2 + u) * 2048 + (c8 >> 2) * 512 + (c8 & 3) * 128 + (rloc & 15) * 8;
        *(uint2*)((char*)b8 + off) = outB;
        *(uint2*)((char*)a8 + off) = outA;
        float s = v0.x * v0.x + v0.y * v0.y + v0.z * v0.z + v0.w * v0.w
                + v1.x * v1.x + v1.y * v1.y + v1.z * v1.z + v1.w * v1.w;
        s += __shfl_xor(s, 1); s += __shfl_xor(s, 2);
        s += __shfl_xor(s, 4); s += __shfl_xor(s, 8);
        if (c8 == 0) { sq[row] = s; myMin = fminf(myMin, s); }
    }
    if ((t & 15) == 0) atomicMin(&tmn, __float_as_int(myMin));
    __syncthreads();
    if (t == 0) tminpart[b] = __int_as_float(tmn);

    // Atomic-free class accumulation: group g (of 4) handles 8 rows into its
    // own LDS copy; thread exclusively owns 2 columns.
    {
        int g = t >> 6, col0 = (t & 63) * 2;
#pragma unroll
        for (int rr = 0; rr < 8; ++rr) {
            int rloc = g * 8 + rr;
            float2 v = *(const float2*)(ys + (size_t)(b * RPB + rloc) * DD + col0);
            int lb = slab[rloc];
            cls[g][lb][col0]     += v.x;
            cls[g][lb][col0 + 1] += v.y;
        }
    }
    __syncthreads();
#pragma unroll
    for (int i = 0; i < 4; ++i) {
        int idx = i * 256 + t;
        float4 s0 = ((const float4*)cls[0])[idx];
        float4 s1 = ((const float4*)cls[1])[idx];
        float4 s2 = ((const float4*)cls[2])[idx];
        float4 s3 = ((const float4*)cls[3])[idx];
        ((float4*)(clspart + (size_t)b * NC * DD))[idx] =
            make_float4((s0.x + s1.x) + (s2.x + s3.x), (s0.y + s1.y) + (s2.y + s3.y),
                        (s0.z + s1.z) + (s2.z + s3.z), (s0.w + s1.w) + (s2.w + s3.w));
    }
    if (b == 0 && t == 0) out[0] = 0.f;
}

// classred_wide: blocks 0..127: (class c = g>>2, col-quarter q = g&3): thread t
// reads pb=t's 32-col slice CONTIGUOUSLY (8 x float4, ILP), LDS tree over pb,
// then atomicAdd(out, -||S||^2_partial * SCALE). Blocks 128..159: class c scan
// of lab/sq -> atomicAdd(out, +cnt*ssq*SCALE). All additive; one atomic/block.
__global__ __launch_bounds__(256) void classred_kernel(const float* __restrict__ clspart,
                                                       const int* __restrict__ lab,
                                                       const float* __restrict__ sq,
                                                       float* __restrict__ out) {
    int g = blockIdx.x, t = threadIdx.x;
    __shared__ float4 red[8][256];   // 32 KB, conflict-free (contiguous per lane)

    if (g < 128) {
        int c = g >> 2, q = g & 3;
        const float4* base = (const float4*)(clspart + (size_t)t * NC * DD + c * DD + q * 32);
        float4 v[8];
#pragma unroll
        for (int j = 0; j < 8; ++j) v[j] = base[j];
#pragma unroll
        for (int j = 0; j < 8; ++j) red[j][t] = v[j];
        __syncthreads();
#pragma unroll
        for (int s = 128; s >= 1; s >>= 1) {
            if (t < s) {
#pragma unroll
                for (int j = 0; j < 8; ++j) {
                    float4 a = red[j][t], b2 = red[j][t + s];
                    red[j][t] = make_float4(a.x + b2.x, a.y + b2.y, a.z + b2.z, a.w + b2.w);
                }
            }
            __syncthreads();
        }
        if (t == 0) {
            float s2 = 0.f;
#pragma unroll
            for (int j = 0; j < 8; ++j) {
                float4 a = red[j][0];
                s2 += a.x * a.x + a.y * a.y + a.z * a.z + a.w * a.w;
            }
            atomicAdd(out, -s2 * SCALE);
        }
    } else {
        int c = g - 128;
        float cnt = 0.f, ssq = 0.f;
#pragma unroll 4
        for (int rr = t; rr < NN; rr += 256) {
            int lb = lab[rr]; float s = sq[rr];
            if (lb == c) { cnt += 1.f; ssq += s; }
        }
#pragma unroll
        for (int off = 32; off >= 1; off >>= 1) {
            cnt += __shfl_down(cnt, off);
            ssq += __shfl_down(ssq, off);
        }
        __shared__ float rc[4], rs[4];
        if ((t & 63) == 0) { rc[t >> 6] = cnt; rs[t >> 6] = ssq; }
        __syncthreads();
        if (t == 0) {
            float C = (rc[0] + rc[1]) + (rc[2] + rc[3]);
            float S = (rs[0] + rs[1]) + (rs[2] + rs[3]);
            atomicAdd(out, C * S * SCALE);
        }
    }
}

// loss: pure tile grid, 2 tiles per block (sequential, registers reused).
// Per tile: fp8 k-loop (R8-exact) -> per-thread min(acc) + tminpart bound ->
// __any gate -> (never-taken) exact slow path from fp32 ys.
__global__ __launch_bounds__(256) void loss_kernel(const uint32_t* __restrict__ a8,
                                                   const uint32_t* __restrict__ b8,
                                                   const float* __restrict__ sq,
                                                   const int* __restrict__ lab,
                                                   const float* __restrict__ tminpart,
                                                   const float* __restrict__ ys,
                                                   float* __restrict__ out) {
    int p = blockIdx.x, t = threadIdx.x;

    // Decode first tile pt0 = 2p -> (bi, bj), bi <= bj (row-major upper-tri).
    int pt0 = p * 2;
    int q = (NBLK - 1) - pt0;
    int r = (int)((sqrtf(8.0f * (float)q + 1.0f) - 1.0f) * 0.5f);
    while (r * (r + 1) / 2 > q) --r;
    while ((r + 1) * (r + 2) / 2 <= q) ++r;
    int bi = (NB - 1) - r;
    int bj = (NB - 1) - (q - r * (r + 1) / 2);

    int wave = t >> 6, lane = t & 63;
    int wm = wave >> 1, wn = wave & 1;
    int lr = lane & 15, lg = lane >> 4;
    int lo = lg * 128 + lr * 8;   // lane offset within a (panel, ks) 512B slab

    float total_ns = 0.f;

#pragma unroll 1
    for (int tt = 0; tt < 2; ++tt) {
        int i0 = bi * 128, j0 = bj * 128;

        // Tile lower bound on sq_i + sq_j: one float4 load + 3 fmin per side.
        float4 ti = ((const float4*)tminpart)[bi];
        float4 tj = ((const float4*)tminpart)[bj];
        float tb = fminf(fminf(ti.x, ti.y), fminf(ti.z, ti.w))
                 + fminf(fminf(tj.x, tj.y), fminf(tj.z, tj.w));

        const char* pa = (const char*)a8 + ((size_t)bi * 8 + wm * 4) * 2048 + lo;
        const char* pbp = (const char*)b8 + ((size_t)bj * 8 + wn * 4) * 2048 + lo;

        f32x4 acc[4][4];
#pragma unroll
        for (int m = 0; m < 4; ++m)
#pragma unroll
            for (int n = 0; n < 4; ++n) acc[m][n] = (f32x4){0.f, 0.f, 0.f, 0.f};

#pragma unroll
        for (int ks = 0; ks < 4; ++ks) {
            long af[4], bf[4];
#pragma unroll
            for (int m = 0; m < 4; ++m) af[m] = *(const long*)(pa + m * 2048 + ks * 512);
#pragma unroll
            for (int n = 0; n < 4; ++n) bf[n] = *(const long*)(pbp + n * 2048 + ks * 512);
#pragma unroll
            for (int m = 0; m < 4; ++m)
#pragma unroll
                for (int n = 0; n < 4; ++n)
                    acc[m][n] = __builtin_amdgcn_mfma_f32_16x16x32_fp8_fp8(af[m], bf[n], acc[m][n], 0, 0, 0);
        }

        // Per-thread min over the 16 values; no cross-lane shuffles needed.
        float mn = acc[0][0][0];
#pragma unroll
        for (int m = 0; m < 4; ++m)
#pragma unroll
            for (int n = 0; n < 4; ++n)
#pragma unroll
                for (int qq = 0; qq < 4; ++qq) mn = fminf(mn, acc[m][n][qq]);

        if (__any(mn + tb < 20.0f)) {
            // Slow path (fires only on diagonal tiles' i==j entries; exact check).
#pragma unroll
            for (int m = 0; m < 4; ++m)
#pragma unroll
                for (int n = 0; n < 4; ++n)
#pragma unroll
                    for (int qq = 0; qq < 4; ++qq) {
                        int i = i0 + wm * 64 + m * 16 + lg * 4 + qq;
                        int j = j0 + wn * 64 + n * 16 + lr;
                        if (i < j) {
                            float d2a = acc[m][n][qq] + sq[i] + sq[j];
                            if (d2a < 20.0f && lab[i] != lab[j]) {
                                float d2e = 0.f;
                                for (int d = 0; d < DD; ++d) {
                                    float df = ys[(size_t)i * DD + d] - ys[(size_t)j * DD + d];
                                    d2e += df * df;
                                }
                                if (d2e < 1.0f) { float e = 1.0f - sqrtf(d2e); total_ns += e * e; }
                            }
                        }
                    }
        }

        // Advance to next tile (row-major upper-tri).
        ++bj;
        if (bj == NB) { ++bi; bj = bi; }
    }

    if (total_ns != 0.f) atomicAdd(out, total_ns * SCALE);
}

extern "C" void kernel_launch(void* const* d_in, const int* in_sizes, int n_in,
                              void* d_out, int out_size, void* d_ws, size_t ws_size,
                              hipStream_t stream) {
    const float* ys = (const float*)d_in[0];
    const int* lab = (const int*)d_in[1];
    float* out = (float*)d_out;

    char* w = (char*)d_ws;
    uint32_t* a8     = (uint32_t*)(w);                 // 1 MB (-2y fp8, frag-major)
    uint32_t* b8     = (uint32_t*)(w + 1048576);       // 1 MB (y fp8)
    float* sq        = (float*)(w + 2097152);          // 32 KB
    float* clspart   = (float*)(w + 2129920);          // 4 MB
    float* tminpart  = (float*)(w + 6324224);          // 1 KB

    prep_kernel<<<NPB, 256, 0, stream>>>(ys, lab, a8, b8, sq, clspart, tminpart, out);
    classred_kernel<<<160, 256, 0, stream>>>(clspart, lab, sq, out);
    loss_kernel<<<NTB, 256, 0, stream>>>(a8, b8, sq, lab, tminpart, ys, out);
}

// Round 13
// 38.485 us; speedup vs baseline: 1.6913x; 1.0633x over previous
//
#include <hip/hip_runtime.h>
#include <stdint.h>
#include <math.h>

#define NN 8192
#define DD 128
#define NB 64                    // 8192/128 tiles per dim
#define NBLK (NB * (NB + 1) / 2) // 2080 upper-triangular tile blocks (= 8*260)
#define NC 32                    // classes
#define NPB 256                  // prep blocks (= class partial blocks)
#define RPB 32                   // rows per prep block
#define SCALE (2.0f / ((float)NN * (float)(NN - 1)))

typedef __attribute__((ext_vector_type(4))) float f32x4;

// fp8 e4m3 fragment-major layout (for mfma_f32_16x16x32_fp8_fp8):
// panel = row>>4; byte(row,k) = panel*2048 + (k>>5)*512 + ((k>>3)&3)*128 + (row&15)*8 + (k&7)

__device__ __forceinline__ uint32_t pk4_fp8(float f0, float f1, float f2, float f3) {
    int d = __builtin_amdgcn_cvt_pk_fp8_f32(f0, f1, 0, false);   // bytes 0,1
    d = __builtin_amdgcn_cvt_pk_fp8_f32(f2, f3, d, true);        // bytes 2,3
    return (uint32_t)d;
}

// prep: R12-validated (fp8 frag-major cast + row norms + class partials + tminpart).
__global__ __launch_bounds__(256) void prep_kernel(const float* __restrict__ ys,
                                                   const int* __restrict__ lab,
                                                   uint32_t* __restrict__ a8,
                                                   uint32_t* __restrict__ b8,
                                                   float* __restrict__ sq,
                                                   float* __restrict__ clspart,
                                                   float* __restrict__ tminpart,
                                                   float* __restrict__ out) {
    int b = blockIdx.x, t = threadIdx.x;
    __shared__ float cls[4][NC][DD];   // 64 KB
    __shared__ int slab[RPB];
    __shared__ int tmn;

#pragma unroll
    for (int i = 0; i < 16; ++i) ((float4*)cls)[i * 256 + t] = make_float4(0.f, 0.f, 0.f, 0.f);
    if (t < RPB) slab[t] = lab[b * RPB + t];
    if (t == 0) tmn = 0x7f800000;   // +inf bits (sq > 0 so int-min == float-min)

    float myMin = 1e30f;
#pragma unroll
    for (int u = 0; u < 2; ++u) {
        int rloc = (t >> 4) + u * 16;   // 0..31
        int c8 = t & 15;                // 8-float chunk within row (k = c8*8)
        int row = b * RPB + rloc;
        const float* base = ys + (size_t)row * DD + c8 * 8;
        float4 v0 = *(const float4*)base;
        float4 v1 = *(const float4*)(base + 4);
        uint2 outB = make_uint2(pk4_fp8(v0.x, v0.y, v0.z, v0.w),
                                pk4_fp8(v1.x, v1.y, v1.z, v1.w));
        uint2 outA = make_uint2(pk4_fp8(-2.f * v0.x, -2.f * v0.y, -2.f * v0.z, -2.f * v0.w),
                                pk4_fp8(-2.f * v1.x, -2.f * v1.y, -2.f * v1.z, -2.f * v1.w));
        size_t off = (size_t)(b * 2 + u) * 2048 + (c8 >> 2) * 512 + (c8 & 3) * 128 + (rloc & 15) * 8;
        *(uint2*)((char*)b8 + off) = outB;
        *(uint2*)((char*)a8 + off) = outA;
        float s = v0.x * v0.x + v0.y * v0.y + v0.z * v0.z + v0.w * v0.w
                + v1.x * v1.x + v1.y * v1.y + v1.z * v1.z + v1.w * v1.w;
        s += __shfl_xor(s, 1); s += __shfl_xor(s, 2);
        s += __shfl_xor(s, 4); s += __shfl_xor(s, 8);
        if (c8 == 0) { sq[row] = s; myMin = fminf(myMin, s); }
    }
    if ((t & 15) == 0) atomicMin(&tmn, __float_as_int(myMin));
    __syncthreads();
    if (t == 0) tminpart[b] = __int_as_float(tmn);

    // Atomic-free class accumulation: group g (of 4) handles 8 rows into its
    // own LDS copy; thread exclusively owns 2 columns.
    {
        int g = t >> 6, col0 = (t & 63) * 2;
#pragma unroll
        for (int rr = 0; rr < 8; ++rr) {
            int rloc = g * 8 + rr;
            float2 v = *(const float2*)(ys + (size_t)(b * RPB + rloc) * DD + col0);
            int lb = slab[rloc];
            cls[g][lb][col0]     += v.x;
            cls[g][lb][col0 + 1] += v.y;
        }
    }
    __syncthreads();
#pragma unroll
    for (int i = 0; i < 4; ++i) {
        int idx = i * 256 + t;
        float4 s0 = ((const float4*)cls[0])[idx];
        float4 s1 = ((const float4*)cls[1])[idx];
        float4 s2 = ((const float4*)cls[2])[idx];
        float4 s3 = ((const float4*)cls[3])[idx];
        ((float4*)(clspart + (size_t)b * NC * DD))[idx] =
            make_float4((s0.x + s1.x) + (s2.x + s3.x), (s0.y + s1.y) + (s2.y + s3.y),
                        (s0.z + s1.z) + (s2.z + s3.z), (s0.w + s1.w) + (s2.w + s3.w));
    }
    if (b == 0 && t == 0) out[0] = 0.f;
}

// classred_wide (R12-validated): blocks 0..127: thread t reads pb=t's 32-col
// slice contiguously, LDS tree over pb, atomicAdd(out, -||S||^2_partial*SCALE).
// Blocks 128..159: class scan of lab/sq -> atomicAdd(out, +cnt*ssq*SCALE).
__global__ __launch_bounds__(256) void classred_kernel(const float* __restrict__ clspart,
                                                       const int* __restrict__ lab,
                                                       const float* __restrict__ sq,
                                                       float* __restrict__ out) {
    int g = blockIdx.x, t = threadIdx.x;
    __shared__ float4 red[8][256];   // 32 KB

    if (g < 128) {
        int c = g >> 2, q = g & 3;
        const float4* base = (const float4*)(clspart + (size_t)t * NC * DD + c * DD + q * 32);
        float4 v[8];
#pragma unroll
        for (int j = 0; j < 8; ++j) v[j] = base[j];
#pragma unroll
        for (int j = 0; j < 8; ++j) red[j][t] = v[j];
        __syncthreads();
#pragma unroll
        for (int s = 128; s >= 1; s >>= 1) {
            if (t < s) {
#pragma unroll
                for (int j = 0; j < 8; ++j) {
                    float4 a = red[j][t], b2 = red[j][t + s];
                    red[j][t] = make_float4(a.x + b2.x, a.y + b2.y, a.z + b2.z, a.w + b2.w);
                }
            }
            __syncthreads();
        }
        if (t == 0) {
            float s2 = 0.f;
#pragma unroll
            for (int j = 0; j < 8; ++j) {
                float4 a = red[j][0];
                s2 += a.x * a.x + a.y * a.y + a.z * a.z + a.w * a.w;
            }
            atomicAdd(out, -s2 * SCALE);
        }
    } else {
        int c = g - 128;
        float cnt = 0.f, ssq = 0.f;
#pragma unroll 4
        for (int rr = t; rr < NN; rr += 256) {
            int lb = lab[rr]; float s = sq[rr];
            if (lb == c) { cnt += 1.f; ssq += s; }
        }
#pragma unroll
        for (int off = 32; off >= 1; off >>= 1) {
            cnt += __shfl_down(cnt, off);
            ssq += __shfl_down(ssq, off);
        }
        __shared__ float rc[4], rs[4];
        if ((t & 63) == 0) { rc[t >> 6] = cnt; rs[t >> 6] = ssq; }
        __syncthreads();
        if (t == 0) {
            float C = (rc[0] + rc[1]) + (rc[2] + rc[3]);
            float S = (rs[0] + rs[1]) + (rs[2] + rs[3]);
            atomicAdd(out, C * S * SCALE);
        }
    }
}

// loss: PURE tile grid, 2080 blocks, one 128x128 tile each (R8's proven path),
// XCD-swizzled (2080 = 8*260, bijective). fp8 k-loop; tminpart epilogue bound;
// never-taken exact slow path (i<j first).
__global__ __launch_bounds__(256) void loss_kernel(const uint32_t* __restrict__ a8,
                                                   const uint32_t* __restrict__ b8,
                                                   const float* __restrict__ sq,
                                                   const int* __restrict__ lab,
                                                   const float* __restrict__ tminpart,
                                                   const float* __restrict__ ys,
                                                   float* __restrict__ out) {
    int bid = blockIdx.x, t = threadIdx.x;
    int p = (bid & 7) * 260 + (bid >> 3);   // bijective XCD swizzle

    // Triangular decode: p -> (bi, bj), bi <= bj (row-major upper-tri).
    int q = (NBLK - 1) - p;
    int r = (int)((sqrtf(8.0f * (float)q + 1.0f) - 1.0f) * 0.5f);
    while (r * (r + 1) / 2 > q) --r;
    while ((r + 1) * (r + 2) / 2 <= q) ++r;
    int bi = (NB - 1) - r;
    int bj = (NB - 1) - (q - r * (r + 1) / 2);
    int i0 = bi * 128, j0 = bj * 128;

    int wave = t >> 6, lane = t & 63;
    int wm = wave >> 1, wn = wave & 1;
    int lr = lane & 15, lg = lane >> 4;
    int lo = lg * 128 + lr * 8;   // lane offset within a (panel, ks) 512B slab

    // Tile lower bound on sq_i + sq_j (one float4 + 3 fmin per side).
    float4 ti = ((const float4*)tminpart)[bi];
    float4 tj = ((const float4*)tminpart)[bj];
    float tb = fminf(fminf(ti.x, ti.y), fminf(ti.z, ti.w))
             + fminf(fminf(tj.x, tj.y), fminf(tj.z, tj.w));

    const char* pa = (const char*)a8 + ((size_t)bi * 8 + wm * 4) * 2048 + lo;
    const char* pbp = (const char*)b8 + ((size_t)bj * 8 + wn * 4) * 2048 + lo;

    f32x4 acc[4][4];
#pragma unroll
    for (int m = 0; m < 4; ++m)
#pragma unroll
        for (int n = 0; n < 4; ++n) acc[m][n] = (f32x4){0.f, 0.f, 0.f, 0.f};

#pragma unroll
    for (int ks = 0; ks < 4; ++ks) {
        long af[4], bf[4];
#pragma unroll
        for (int m = 0; m < 4; ++m) af[m] = *(const long*)(pa + m * 2048 + ks * 512);
#pragma unroll
        for (int n = 0; n < 4; ++n) bf[n] = *(const long*)(pbp + n * 2048 + ks * 512);
#pragma unroll
        for (int m = 0; m < 4; ++m)
#pragma unroll
            for (int n = 0; n < 4; ++n)
                acc[m][n] = __builtin_amdgcn_mfma_f32_16x16x32_fp8_fp8(af[m], bf[n], acc[m][n], 0, 0, 0);
    }

    // Per-thread min over the 16 acc values; no cross-lane ops.
    float mn = acc[0][0][0];
#pragma unroll
    for (int m = 0; m < 4; ++m)
#pragma unroll
        for (int n = 0; n < 4; ++n)
#pragma unroll
            for (int qq = 0; qq < 4; ++qq) mn = fminf(mn, acc[m][n][qq]);

    if (__any(mn + tb < 20.0f)) {
        // Slow path (diagonal i==j short-circuits on i<j; exact re-check from ys).
        float ns = 0.f;
#pragma unroll
        for (int m = 0; m < 4; ++m)
#pragma unroll
            for (int n = 0; n < 4; ++n)
#pragma unroll
                for (int qq = 0; qq < 4; ++qq) {
                    int i = i0 + wm * 64 + m * 16 + lg * 4 + qq;
                    int j = j0 + wn * 64 + n * 16 + lr;
                    if (i < j) {
                        float d2a = acc[m][n][qq] + sq[i] + sq[j];
                        if (d2a < 20.0f && lab[i] != lab[j]) {
                            float d2e = 0.f;
                            for (int d = 0; d < DD; ++d) {
                                float df = ys[(size_t)i * DD + d] - ys[(size_t)j * DD + d];
                                d2e += df * df;
                            }
                            if (d2e < 1.0f) { float e = 1.0f - sqrtf(d2e); ns += e * e; }
                        }
                    }
                }
        if (ns != 0.f) atomicAdd(out, ns * SCALE);
    }
}

extern "C" void kernel_launch(void* const* d_in, const int* in_sizes, int n_in,
                              void* d_out, int out_size, void* d_ws, size_t ws_size,
                              hipStream_t stream) {
    const float* ys = (const float*)d_in[0];
    const int* lab = (const int*)d_in[1];
    float* out = (float*)d_out;

    char* w = (char*)d_ws;
    uint32_t* a8     = (uint32_t*)(w);                 // 1 MB (-2y fp8, frag-major)
    uint32_t* b8     = (uint32_t*)(w + 1048576);       // 1 MB (y fp8)
    float* sq        = (float*)(w + 2097152);          // 32 KB
    float* clspart   = (float*)(w + 2129920);          // 4 MB
    float* tminpart  = (float*)(w + 6324224);          // 1 KB

    prep_kernel<<<NPB, 256, 0, stream>>>(ys, lab, a8, b8, sq, clspart, tminpart, out);
    classred_kernel<<<160, 256, 0, stream>>>(clspart, lab, sq, out);
    loss_kernel<<<NBLK, 256, 0, stream>>>(a8, b8, sq, lab, tminpart, ys, out);
}

// Round 14
// 36.833 us; speedup vs baseline: 1.7672x; 1.0449x over previous
//
#include <hip/hip_runtime.h>
#include <stdint.h>
#include <math.h>

#define NN 8192
#define DD 128
#define BT 256                    // big tile dim
#define NB2 (NN / BT)             // 32 tiles per dim
#define NBLK2 (NB2 * (NB2 + 1) / 2) // 528 upper-triangular tile blocks
#define NC 32                     // classes
#define NPB 256                   // prep blocks (= class partial blocks)
#define RPB 32                    // rows per prep block
#define TOT2 (NBLK2 + NC)         // fused loss grid: 560
#define SCALE (2.0f / ((float)NN * (float)(NN - 1)))

typedef __attribute__((ext_vector_type(4))) float f32x4;

// fp8 e4m3 fragment-major layout (for mfma_f32_16x16x32_fp8_fp8):
// panel = row>>4; byte(row,k) = panel*2048 + (k>>5)*512 + ((k>>3)&3)*128 + (row&15)*8 + (k&7)

__device__ __forceinline__ uint32_t pk4_fp8(float f0, float f1, float f2, float f3) {
    int d = __builtin_amdgcn_cvt_pk_fp8_f32(f0, f1, 0, false);   // bytes 0,1
    d = __builtin_amdgcn_cvt_pk_fp8_f32(f2, f3, d, true);        // bytes 2,3
    return (uint32_t)d;
}

// prep: R12/R13-validated (fp8 frag-major cast + row norms + class partials + tminpart).
__global__ __launch_bounds__(256) void prep_kernel(const float* __restrict__ ys,
                                                   const int* __restrict__ lab,
                                                   uint32_t* __restrict__ a8,
                                                   uint32_t* __restrict__ b8,
                                                   float* __restrict__ sq,
                                                   float* __restrict__ clspart,
                                                   float* __restrict__ tminpart,
                                                   float* __restrict__ out) {
    int b = blockIdx.x, t = threadIdx.x;
    __shared__ float cls[4][NC][DD];   // 64 KB
    __shared__ int slab[RPB];
    __shared__ int tmn;

#pragma unroll
    for (int i = 0; i < 16; ++i) ((float4*)cls)[i * 256 + t] = make_float4(0.f, 0.f, 0.f, 0.f);
    if (t < RPB) slab[t] = lab[b * RPB + t];
    if (t == 0) tmn = 0x7f800000;   // +inf bits (sq > 0 so int-min == float-min)

    float myMin = 1e30f;
#pragma unroll
    for (int u = 0; u < 2; ++u) {
        int rloc = (t >> 4) + u * 16;   // 0..31
        int c8 = t & 15;                // 8-float chunk within row (k = c8*8)
        int row = b * RPB + rloc;
        const float* base = ys + (size_t)row * DD + c8 * 8;
        float4 v0 = *(const float4*)base;
        float4 v1 = *(const float4*)(base + 4);
        uint2 outB = make_uint2(pk4_fp8(v0.x, v0.y, v0.z, v0.w),
                                pk4_fp8(v1.x, v1.y, v1.z, v1.w));
        uint2 outA = make_uint2(pk4_fp8(-2.f * v0.x, -2.f * v0.y, -2.f * v0.z, -2.f * v0.w),
                                pk4_fp8(-2.f * v1.x, -2.f * v1.y, -2.f * v1.z, -2.f * v1.w));
        size_t off = (size_t)(b * 2 + u) * 2048 + (c8 >> 2) * 512 + (c8 & 3) * 128 + (rloc & 15) * 8;
        *(uint2*)((char*)b8 + off) = outB;
        *(uint2*)((char*)a8 + off) = outA;
        float s = v0.x * v0.x + v0.y * v0.y + v0.z * v0.z + v0.w * v0.w
                + v1.x * v1.x + v1.y * v1.y + v1.z * v1.z + v1.w * v1.w;
        s += __shfl_xor(s, 1); s += __shfl_xor(s, 2);
        s += __shfl_xor(s, 4); s += __shfl_xor(s, 8);
        if (c8 == 0) { sq[row] = s; myMin = fminf(myMin, s); }
    }
    if ((t & 15) == 0) atomicMin(&tmn, __float_as_int(myMin));
    __syncthreads();
    if (t == 0) tminpart[b] = __int_as_float(tmn);

    // Atomic-free class accumulation: group g (of 4) handles 8 rows into its
    // own LDS copy; thread exclusively owns 2 columns.
    {
        int g = t >> 6, col0 = (t & 63) * 2;
#pragma unroll
        for (int rr = 0; rr < 8; ++rr) {
            int rloc = g * 8 + rr;
            float2 v = *(const float2*)(ys + (size_t)(b * RPB + rloc) * DD + col0);
            int lb = slab[rloc];
            cls[g][lb][col0]     += v.x;
            cls[g][lb][col0 + 1] += v.y;
        }
    }
    __syncthreads();
#pragma unroll
    for (int i = 0; i < 4; ++i) {
        int idx = i * 256 + t;
        float4 s0 = ((const float4*)cls[0])[idx];
        float4 s1 = ((const float4*)cls[1])[idx];
        float4 s2 = ((const float4*)cls[2])[idx];
        float4 s3 = ((const float4*)cls[3])[idx];
        ((float4*)(clspart + (size_t)b * NC * DD))[idx] =
            make_float4((s0.x + s1.x) + (s2.x + s3.x), (s0.y + s1.y) + (s2.y + s3.y),
                        (s0.z + s1.z) + (s2.z + s3.z), (s0.w + s1.w) + (s2.w + s3.w));
    }
    if (b == 0 && t == 0) out[0] = 0.f;
}

// Fused loss, 512 threads/block. Blocks 0..31: classred -> atomicAdd(out).
// Blocks 32..559: one 256x256 tile, 8 waves (2m x 4n), acc[8][4], fp8 MFMA.
__global__ __launch_bounds__(512, 2) void loss_kernel(const uint32_t* __restrict__ a8,
                                                      const uint32_t* __restrict__ b8,
                                                      const float* __restrict__ sq,
                                                      const int* __restrict__ lab,
                                                      const float* __restrict__ clspart,
                                                      const float* __restrict__ tminpart,
                                                      const float* __restrict__ ys,
                                                      float* __restrict__ out) {
    int p = blockIdx.x, t = threadIdx.x;

    if (p < NC) {
        // ---- classred for class p: pos_c = n_c*ssq_c - ||S_c||^2 ----
        __shared__ float sp[4][DD];
        __shared__ float rc[8], rs[8], red2[2];
        int col = t & 127, grp = t >> 7;   // 4 pb-groups of 64
        const float* cp = clspart + (size_t)(grp * 64) * NC * DD + p * DD + col;
        float S0 = 0.f, S1 = 0.f, S2 = 0.f, S3 = 0.f;
#pragma unroll 4
        for (int pb = 0; pb < 64; pb += 4) {
            S0 += cp[(size_t)(pb + 0) * NC * DD];
            S1 += cp[(size_t)(pb + 1) * NC * DD];
            S2 += cp[(size_t)(pb + 2) * NC * DD];
            S3 += cp[(size_t)(pb + 3) * NC * DD];
        }
        sp[grp][col] = (S0 + S1) + (S2 + S3);

        float cnt = 0.f, ssq = 0.f;
#pragma unroll 4
        for (int rr = t; rr < NN; rr += 512) {
            if (lab[rr] == p) { cnt += 1.f; ssq += sq[rr]; }
        }
#pragma unroll
        for (int off = 32; off >= 1; off >>= 1) {
            cnt += __shfl_down(cnt, off);
            ssq += __shfl_down(ssq, off);
        }
        if ((t & 63) == 0) { rc[t >> 6] = cnt; rs[t >> 6] = ssq; }
        __syncthreads();

        float s2 = 0.f;
        if (t < DD) {
            float Sc = (sp[0][t] + sp[1][t]) + (sp[2][t] + sp[3][t]);
            s2 = Sc * Sc;
        }
#pragma unroll
        for (int off = 32; off >= 1; off >>= 1) s2 += __shfl_down(s2, off);
        if (t < 128 && (t & 63) == 0) red2[t >> 6] = s2;
        __syncthreads();
        if (t == 0) {
            float C = ((rc[0] + rc[1]) + (rc[2] + rc[3])) + ((rc[4] + rc[5]) + (rc[6] + rc[7]));
            float S = ((rs[0] + rs[1]) + (rs[2] + rs[3])) + ((rs[4] + rs[5]) + (rs[6] + rs[7]));
            atomicAdd(out, (C * S - (red2[0] + red2[1])) * SCALE);
        }
        return;
    }

    // ---- 256x256 tile GEMM ----
    int pt = p - NC;
    int q = (NBLK2 - 1) - pt;
    int r = (int)((sqrtf(8.0f * (float)q + 1.0f) - 1.0f) * 0.5f);
    while (r * (r + 1) / 2 > q) --r;
    while ((r + 1) * (r + 2) / 2 <= q) ++r;
    int bi = (NB2 - 1) - r;
    int bj = (NB2 - 1) - (q - r * (r + 1) / 2);
    int i0 = bi * BT, j0 = bj * BT;

    int wave = t >> 6, lane = t & 63;
    int wm = wave >> 2, wn = wave & 3;   // 2 x 4 wave grid; wave tile 128 x 64
    int lr = lane & 15, lg = lane >> 4;
    int lo = lg * 128 + lr * 8;          // lane offset within a (panel, ks) 512B slab

    // Tile lower bound on sq_i + sq_j from tminpart (8 entries per side).
    float tb;
    {
        const float4* tp = (const float4*)tminpart;
        float4 a0 = tp[bi * 2], a1 = tp[bi * 2 + 1];
        float4 c0 = tp[bj * 2], c1 = tp[bj * 2 + 1];
        float mi = fminf(fminf(fminf(a0.x, a0.y), fminf(a0.z, a0.w)),
                         fminf(fminf(a1.x, a1.y), fminf(a1.z, a1.w)));
        float mj = fminf(fminf(fminf(c0.x, c0.y), fminf(c0.z, c0.w)),
                         fminf(fminf(c1.x, c1.y), fminf(c1.z, c1.w)));
        tb = mi + mj;
    }

    const char* pa = (const char*)a8 + ((size_t)bi * 16 + wm * 8) * 2048 + lo;
    const char* pbp = (const char*)b8 + ((size_t)bj * 16 + wn * 4) * 2048 + lo;

    f32x4 acc[8][4];
#pragma unroll
    for (int m = 0; m < 8; ++m)
#pragma unroll
        for (int n = 0; n < 4; ++n) acc[m][n] = (f32x4){0.f, 0.f, 0.f, 0.f};

#pragma unroll
    for (int ks = 0; ks < 4; ++ks) {
        long af[8], bf[4];
#pragma unroll
        for (int m = 0; m < 8; ++m) af[m] = *(const long*)(pa + m * 2048 + ks * 512);
#pragma unroll
        for (int n = 0; n < 4; ++n) bf[n] = *(const long*)(pbp + n * 2048 + ks * 512);
#pragma unroll
        for (int m = 0; m < 8; ++m)
#pragma unroll
            for (int n = 0; n < 4; ++n)
                acc[m][n] = __builtin_amdgcn_mfma_f32_16x16x32_fp8_fp8(af[m], bf[n], acc[m][n], 0, 0, 0);
    }

    // Per-thread min over 128 acc values, 4-way ILP.
    float m0 = acc[0][0][0], m1 = acc[0][0][1], m2 = acc[0][0][2], m3 = acc[0][0][3];
#pragma unroll
    for (int m = 0; m < 8; ++m)
#pragma unroll
        for (int n = 0; n < 4; ++n) {
            m0 = fminf(m0, acc[m][n][0]);
            m1 = fminf(m1, acc[m][n][1]);
            m2 = fminf(m2, acc[m][n][2]);
            m3 = fminf(m3, acc[m][n][3]);
        }
    float mn = fminf(fminf(m0, m1), fminf(m2, m3));

    if (__any(mn + tb < 20.0f)) {
        // Slow path (diagonal i==j short-circuits on i<j; exact re-check from ys).
        float ns = 0.f;
#pragma unroll
        for (int m = 0; m < 8; ++m)
#pragma unroll
            for (int n = 0; n < 4; ++n)
#pragma unroll
                for (int qq = 0; qq < 4; ++qq) {
                    int i = i0 + wm * 128 + m * 16 + lg * 4 + qq;
                    int j = j0 + wn * 64 + n * 16 + lr;
                    if (i < j) {
                        float d2a = acc[m][n][qq] + sq[i] + sq[j];
                        if (d2a < 20.0f && lab[i] != lab[j]) {
                            float d2e = 0.f;
                            for (int d = 0; d < DD; ++d) {
                                float df = ys[(size_t)i * DD + d] - ys[(size_t)j * DD + d];
                                d2e += df * df;
                            }
                            if (d2e < 1.0f) { float e = 1.0f - sqrtf(d2e); ns += e * e; }
                        }
                    }
                }
        if (ns != 0.f) atomicAdd(out, ns * SCALE);
    }
}

extern "C" void kernel_launch(void* const* d_in, const int* in_sizes, int n_in,
                              void* d_out, int out_size, void* d_ws, size_t ws_size,
                              hipStream_t stream) {
    const float* ys = (const float*)d_in[0];
    const int* lab = (const int*)d_in[1];
    float* out = (float*)d_out;

    char* w = (char*)d_ws;
    uint32_t* a8     = (uint32_t*)(w);                 // 1 MB (-2y fp8, frag-major)
    uint32_t* b8     = (uint32_t*)(w + 1048576);       // 1 MB (y fp8)
    float* sq        = (float*)(w + 2097152);          // 32 KB
    float* clspart   = (float*)(w + 2129920);          // 4 MB
    float* tminpart  = (float*)(w + 6324224);          // 1 KB

    prep_kernel<<<NPB, 256, 0, stream>>>(ys, lab, a8, b8, sq, clspart, tminpart, out);
    loss_kernel<<<TOT2, 512, 0, stream>>>(a8, b8, sq, lab, clspart, tminpart, ys, out);
}

// Round 15
// 35.421 us; speedup vs baseline: 1.8376x; 1.0398x over previous
//
#include <hip/hip_runtime.h>
#include <stdint.h>
#include <math.h>

#define NN 8192
#define DD 128
#define NB 64                    // 8192/128 tiles per dim
#define NBLK (NB * (NB + 1) / 2) // 2080 upper-triangular tile blocks
#define NC 32                    // classes
#define NPB 256                  // prep blocks (= class partial blocks)
#define RPB 32                   // rows per prep block
#define TOTBLK (NBLK + NC)       // fused loss grid
#define SCALE (2.0f / ((float)NN * (float)(NN - 1)))

typedef __attribute__((ext_vector_type(4))) float f32x4;

// fp8 e4m3 ks-PAIRED fragment-major layout (for mfma_f32_16x16x32_fp8_fp8):
// panel = row>>4 (16 rows x 128 k = 2048 B)
// byte(row,k) = panel*2048 + (k>>6)*1024 + ((k>>3)&3)*256 + (row&15)*16 + ((k>>5)&1)*8 + (k&7)
// -> lane (lr,lg) reads ONE 16-B long2 at panel*2048 + p2*1024 + lg*256 + lr*16:
//    .x = fragment for ks=2*p2, .y = fragment for ks=2*p2+1  (halves the load count)

__device__ __forceinline__ uint32_t pk4_fp8(float f0, float f1, float f2, float f3) {
    int d = __builtin_amdgcn_cvt_pk_fp8_f32(f0, f1, 0, false);   // bytes 0,1
    d = __builtin_amdgcn_cvt_pk_fp8_f32(f2, f3, d, true);        // bytes 2,3
    return (uint32_t)d;
}

// prep: fp8 cast (ks-paired layout) + exact row norms + class partials + tminpart.
__global__ __launch_bounds__(256) void prep_kernel(const float* __restrict__ ys,
                                                   const int* __restrict__ lab,
                                                   uint32_t* __restrict__ a8,
                                                   uint32_t* __restrict__ b8,
                                                   float* __restrict__ sq,
                                                   float* __restrict__ clspart,
                                                   float* __restrict__ tminpart,
                                                   float* __restrict__ out) {
    int b = blockIdx.x, t = threadIdx.x;
    __shared__ float cls[4][NC][DD];   // 64 KB
    __shared__ int slab[RPB];
    __shared__ int tmn;

#pragma unroll
    for (int i = 0; i < 16; ++i) ((float4*)cls)[i * 256 + t] = make_float4(0.f, 0.f, 0.f, 0.f);
    if (t < RPB) slab[t] = lab[b * RPB + t];
    if (t == 0) tmn = 0x7f800000;   // +inf bits (sq > 0 so int-min == float-min)

    float myMin = 1e30f;
#pragma unroll
    for (int u = 0; u < 2; ++u) {
        int rloc = (t >> 4) + u * 16;   // 0..31
        int c8 = t & 15;                // 8-float k-chunk (k = c8*8 .. c8*8+7)
        int row = b * RPB + rloc;
        const float* base = ys + (size_t)row * DD + c8 * 8;
        float4 v0 = *(const float4*)base;
        float4 v1 = *(const float4*)(base + 4);
        uint2 outB = make_uint2(pk4_fp8(v0.x, v0.y, v0.z, v0.w),
                                pk4_fp8(v1.x, v1.y, v1.z, v1.w));
        uint2 outA = make_uint2(pk4_fp8(-2.f * v0.x, -2.f * v0.y, -2.f * v0.z, -2.f * v0.w),
                                pk4_fp8(-2.f * v1.x, -2.f * v1.y, -2.f * v1.z, -2.f * v1.w));
        // ks-paired offset: p2 = c8>>3, lg = c8&3, sub = (c8>>2)&1.
        size_t off = (size_t)(b * 2 + u) * 2048 + (c8 >> 3) * 1024 + (c8 & 3) * 256
                   + (rloc & 15) * 16 + ((c8 >> 2) & 1) * 8;
        *(uint2*)((char*)b8 + off) = outB;
        *(uint2*)((char*)a8 + off) = outA;
        float s = v0.x * v0.x + v0.y * v0.y + v0.z * v0.z + v0.w * v0.w
                + v1.x * v1.x + v1.y * v1.y + v1.z * v1.z + v1.w * v1.w;
        s += __shfl_xor(s, 1); s += __shfl_xor(s, 2);
        s += __shfl_xor(s, 4); s += __shfl_xor(s, 8);
        if (c8 == 0) { sq[row] = s; myMin = fminf(myMin, s); }
    }
    if ((t & 15) == 0) atomicMin(&tmn, __float_as_int(myMin));
    __syncthreads();
    if (t == 0) tminpart[b] = __int_as_float(tmn);

    // Atomic-free class accumulation: group g (of 4) handles 8 rows into its
    // own LDS copy; thread exclusively owns 2 columns.
    {
        int g = t >> 6, col0 = (t & 63) * 2;
#pragma unroll
        for (int rr = 0; rr < 8; ++rr) {
            int rloc = g * 8 + rr;
            float2 v = *(const float2*)(ys + (size_t)(b * RPB + rloc) * DD + col0);
            int lb = slab[rloc];
            cls[g][lb][col0]     += v.x;
            cls[g][lb][col0 + 1] += v.y;
        }
    }
    __syncthreads();
#pragma unroll
    for (int i = 0; i < 4; ++i) {
        int idx = i * 256 + t;
        float4 s0 = ((const float4*)cls[0])[idx];
        float4 s1 = ((const float4*)cls[1])[idx];
        float4 s2 = ((const float4*)cls[2])[idx];
        float4 s3 = ((const float4*)cls[3])[idx];
        ((float4*)(clspart + (size_t)b * NC * DD))[idx] =
            make_float4((s0.x + s1.x) + (s2.x + s3.x), (s0.y + s1.y) + (s2.y + s3.y),
                        (s0.z + s1.z) + (s2.z + s3.z), (s0.w + s1.w) + (s2.w + s3.w));
    }
    if (b == 0 && t == 0) out[0] = 0.f;
}

// Fused loss (R8 structure): blocks 0..31 classred -> atomicAdd(out);
// blocks 32..2111 one 128x128 tile, fp8 MFMA, ks-paired 16-B fragment loads.
__global__ __launch_bounds__(256) void loss_kernel(const uint32_t* __restrict__ a8,
                                                   const uint32_t* __restrict__ b8,
                                                   const float* __restrict__ sq,
                                                   const int* __restrict__ lab,
                                                   const float* __restrict__ clspart,
                                                   const float* __restrict__ tminpart,
                                                   const float* __restrict__ ys,
                                                   float* __restrict__ out) {
    int p = blockIdx.x, t = threadIdx.x;

    if (p < NC) {
        // ---- classred for class p (R8-validated) ----
        __shared__ float sp[2][DD];
        __shared__ float redc[4], reds[4], red2[2];
        int col = t & 127, half = t >> 7;
        float S0 = 0.f, S1 = 0.f, S2 = 0.f, S3 = 0.f;
        const float* cp = clspart + (size_t)half * 128 * NC * DD + p * DD + col;
#pragma unroll 8
        for (int pb = 0; pb < 128; pb += 4) {
            S0 += cp[(size_t)(pb + 0) * NC * DD];
            S1 += cp[(size_t)(pb + 1) * NC * DD];
            S2 += cp[(size_t)(pb + 2) * NC * DD];
            S3 += cp[(size_t)(pb + 3) * NC * DD];
        }
        sp[half][col] = (S0 + S1) + (S2 + S3);

        float cnt = 0.f, ssq = 0.f;
        for (int rr = t; rr < NN; rr += 256) {
            if (lab[rr] == p) { cnt += 1.f; ssq += sq[rr]; }
        }
#pragma unroll
        for (int off = 32; off >= 1; off >>= 1) {
            cnt += __shfl_down(cnt, off);
            ssq += __shfl_down(ssq, off);
        }
        if ((t & 63) == 0) { redc[t >> 6] = cnt; reds[t >> 6] = ssq; }
        __syncthreads();

        float s2 = 0.f;
        if (t < DD) { float Sc = sp[0][t] + sp[1][t]; s2 = Sc * Sc; }
#pragma unroll
        for (int off = 32; off >= 1; off >>= 1) s2 += __shfl_down(s2, off);
        if (t < 128 && (t & 63) == 0) red2[t >> 6] = s2;
        __syncthreads();
        if (t == 0) {
            float c = redc[0] + redc[1] + redc[2] + redc[3];
            float s = reds[0] + reds[1] + reds[2] + reds[3];
            atomicAdd(out, (c * s - (red2[0] + red2[1])) * SCALE);
        }
        return;
    }

    // ---- tile GEMM ----
    int pt = p - NC;
    int q = (NBLK - 1) - pt;
    int r = (int)((sqrtf(8.0f * (float)q + 1.0f) - 1.0f) * 0.5f);
    while (r * (r + 1) / 2 > q) --r;
    while ((r + 1) * (r + 2) / 2 <= q) ++r;
    int bi = (NB - 1) - r;
    int bj = (NB - 1) - (q - r * (r + 1) / 2);
    int i0 = bi * 128, j0 = bj * 128;

    int wave = t >> 6, lane = t & 63;
    int wm = wave >> 1, wn = wave & 1;
    int lr = lane & 15, lg = lane >> 4;
    int lo16 = lg * 256 + lr * 16;   // lane offset within a (panel, pair) 1KB slab

    // Tile lower bound loads issue BEFORE the k-loop (latency hidden under it).
    float4 ti = ((const float4*)tminpart)[bi];
    float4 tj = ((const float4*)tminpart)[bj];

    const char* pa = (const char*)a8 + ((size_t)bi * 8 + wm * 4) * 2048 + lo16;
    const char* pbp = (const char*)b8 + ((size_t)bj * 8 + wn * 4) * 2048 + lo16;

    // All 16 fragment loads issued up front (max MLP); .x = even ks, .y = odd ks.
    long2 A0[4], A1[4], B0[4], B1[4];
#pragma unroll
    for (int m = 0; m < 4; ++m) {
        A0[m] = *(const long2*)(pa + m * 2048);
        A1[m] = *(const long2*)(pa + m * 2048 + 1024);
        B0[m] = *(const long2*)(pbp + m * 2048);
        B1[m] = *(const long2*)(pbp + m * 2048 + 1024);
    }

    f32x4 acc[4][4];
#pragma unroll
    for (int m = 0; m < 4; ++m)
#pragma unroll
        for (int n = 0; n < 4; ++n) acc[m][n] = (f32x4){0.f, 0.f, 0.f, 0.f};

#pragma unroll
    for (int m = 0; m < 4; ++m)
#pragma unroll
        for (int n = 0; n < 4; ++n) {
            acc[m][n] = __builtin_amdgcn_mfma_f32_16x16x32_fp8_fp8(A0[m].x, B0[n].x, acc[m][n], 0, 0, 0);
            acc[m][n] = __builtin_amdgcn_mfma_f32_16x16x32_fp8_fp8(A0[m].y, B0[n].y, acc[m][n], 0, 0, 0);
        }
#pragma unroll
    for (int m = 0; m < 4; ++m)
#pragma unroll
        for (int n = 0; n < 4; ++n) {
            acc[m][n] = __builtin_amdgcn_mfma_f32_16x16x32_fp8_fp8(A1[m].x, B1[n].x, acc[m][n], 0, 0, 0);
            acc[m][n] = __builtin_amdgcn_mfma_f32_16x16x32_fp8_fp8(A1[m].y, B1[n].y, acc[m][n], 0, 0, 0);
        }

    // Bound: per-thread min(acc) + tile min(sq_i) + min(sq_j)  (no cross-lane ops).
    float tb = fminf(fminf(ti.x, ti.y), fminf(ti.z, ti.w))
             + fminf(fminf(tj.x, tj.y), fminf(tj.z, tj.w));
    float mn = acc[0][0][0];
#pragma unroll
    for (int m = 0; m < 4; ++m)
#pragma unroll
        for (int n = 0; n < 4; ++n)
#pragma unroll
            for (int qq = 0; qq < 4; ++qq) mn = fminf(mn, acc[m][n][qq]);

    if (__any(mn + tb < 20.0f)) {
        // Slow path (diagonal-only in practice; exact re-check from fp32 ys).
        float ns = 0.f;
#pragma unroll
        for (int m = 0; m < 4; ++m)
#pragma unroll
            for (int n = 0; n < 4; ++n)
#pragma unroll
                for (int qq = 0; qq < 4; ++qq) {
                    int i = i0 + wm * 64 + m * 16 + lg * 4 + qq;
                    int j = j0 + wn * 64 + n * 16 + lr;
                    if (i < j) {
                        float d2a = acc[m][n][qq] + sq[i] + sq[j];
                        if (d2a < 20.0f && lab[i] != lab[j]) {
                            float d2e = 0.f;
                            for (int d = 0; d < DD; ++d) {
                                float df = ys[(size_t)i * DD + d] - ys[(size_t)j * DD + d];
                                d2e += df * df;
                            }
                            if (d2e < 1.0f) { float e = 1.0f - sqrtf(d2e); ns += e * e; }
                        }
                    }
                }
        if (ns != 0.f) atomicAdd(out, ns * SCALE);
    }
}

extern "C" void kernel_launch(void* const* d_in, const int* in_sizes, int n_in,
                              void* d_out, int out_size, void* d_ws, size_t ws_size,
                              hipStream_t stream) {
    const float* ys = (const float*)d_in[0];
    const int* lab = (const int*)d_in[1];
    float* out = (float*)d_out;

    char* w = (char*)d_ws;
    uint32_t* a8     = (uint32_t*)(w);                 // 1 MB (-2y fp8, ks-paired frag-major)
    uint32_t* b8     = (uint32_t*)(w + 1048576);       // 1 MB (y fp8)
    float* sq        = (float*)(w + 2097152);          // 32 KB
    float* clspart   = (float*)(w + 2129920);          // 4 MB
    float* tminpart  = (float*)(w + 6324224);          // 1 KB

    prep_kernel<<<NPB, 256, 0, stream>>>(ys, lab, a8, b8, sq, clspart, tminpart, out);
    loss_kernel<<<TOTBLK, 256, 0, stream>>>(a8, b8, sq, lab, clspart, tminpart, ys, out);
}

// Round 16
// 32.137 us; speedup vs baseline: 2.0254x; 1.1022x over previous
//
#include <hip/hip_runtime.h>
#include <stdint.h>
#include <math.h>

#define NN 8192
#define DD 128
#define NB 64                    // 8192/128 tiles per dim
#define NBLK (NB * (NB + 1) / 2) // 2080 upper-triangular tile blocks
#define NC 32                    // classes
#define NPB 256                  // prep blocks (= class partial blocks)
#define RPB 32                   // rows per prep block
#define TOTBLK (NBLK + NC)       // fused loss grid
#define SCALE (2.0f / ((float)NN * (float)(NN - 1)))

typedef __attribute__((ext_vector_type(4))) float f32x4;

// fp8 e4m3 fragment-major layout (for mfma_f32_16x16x32_fp8_fp8):
// panel = row>>4; byte(row,k) = panel*2048 + (k>>5)*512 + ((k>>3)&3)*128 + (row&15)*8 + (k&7)
// -> wave-load for (panel, ks): lane l reads 8B at panel*2048 + ks*512 + (l>>4)*128 + (l&15)*8

__device__ __forceinline__ uint32_t pk4_fp8(float f0, float f1, float f2, float f3) {
    int d = __builtin_amdgcn_cvt_pk_fp8_f32(f0, f1, 0, false);   // bytes 0,1
    d = __builtin_amdgcn_cvt_pk_fp8_f32(f2, f3, d, true);        // bytes 2,3
    return (uint32_t)d;
}

// prep: 256 blocks x 32 rows. fp8 cast into a8 (= -2y) / b8 (= y) frag-major +
// exact fp32 row norms + per-block per-class partial sums (4 LDS copies,
// atomic-free: group g owns rows g*8..g*8+7; thread owns 2 columns).
// Also zeroes out[0] (loss kernel atomicAdds into it).
__global__ __launch_bounds__(256) void prep_kernel(const float* __restrict__ ys,
                                                   const int* __restrict__ lab,
                                                   uint32_t* __restrict__ a8,
                                                   uint32_t* __restrict__ b8,
                                                   float* __restrict__ sq,
                                                   float* __restrict__ clspart,
                                                   float* __restrict__ out) {
    int b = blockIdx.x, t = threadIdx.x;
    __shared__ float cls[4][NC][DD];   // 64 KB
    __shared__ int slab[RPB];

#pragma unroll
    for (int i = 0; i < 16; ++i) ((float4*)cls)[i * 256 + t] = make_float4(0.f, 0.f, 0.f, 0.f);
    if (t < RPB) slab[t] = lab[b * RPB + t];

#pragma unroll
    for (int u = 0; u < 2; ++u) {
        int rloc = (t >> 4) + u * 16;   // 0..31
        int c8 = t & 15;                // 8-float chunk within row (k = c8*8)
        int row = b * RPB + rloc;
        const float* base = ys + (size_t)row * DD + c8 * 8;
        float4 v0 = *(const float4*)base;
        float4 v1 = *(const float4*)(base + 4);
        uint2 outB = make_uint2(pk4_fp8(v0.x, v0.y, v0.z, v0.w),
                                pk4_fp8(v1.x, v1.y, v1.z, v1.w));
        uint2 outA = make_uint2(pk4_fp8(-2.f * v0.x, -2.f * v0.y, -2.f * v0.z, -2.f * v0.w),
                                pk4_fp8(-2.f * v1.x, -2.f * v1.y, -2.f * v1.z, -2.f * v1.w));
        size_t off = (size_t)(b * 2 + u) * 2048 + (c8 >> 2) * 512 + (c8 & 3) * 128 + (rloc & 15) * 8;
        *(uint2*)((char*)b8 + off) = outB;
        *(uint2*)((char*)a8 + off) = outA;
        float s = v0.x * v0.x + v0.y * v0.y + v0.z * v0.z + v0.w * v0.w
                + v1.x * v1.x + v1.y * v1.y + v1.z * v1.z + v1.w * v1.w;
        s += __shfl_xor(s, 1); s += __shfl_xor(s, 2);
        s += __shfl_xor(s, 4); s += __shfl_xor(s, 8);
        if (c8 == 0) sq[row] = s;
    }
    __syncthreads();

    // Atomic-free class accumulation: group g (of 4) handles 8 rows into its
    // own LDS copy; thread exclusively owns 2 columns. Chain length 8, 2-way ILP.
    {
        int g = t >> 6, col0 = (t & 63) * 2;
#pragma unroll
        for (int rr = 0; rr < 8; ++rr) {
            int rloc = g * 8 + rr;
            float2 v = *(const float2*)(ys + (size_t)(b * RPB + rloc) * DD + col0);
            int lb = slab[rloc];
            cls[g][lb][col0]     += v.x;
            cls[g][lb][col0 + 1] += v.y;
        }
    }
    __syncthreads();
#pragma unroll
    for (int i = 0; i < 4; ++i) {
        int idx = i * 256 + t;   // float4 index into [NC][DD] (1024 total)
        float4 s0 = ((const float4*)cls[0])[idx];
        float4 s1 = ((const float4*)cls[1])[idx];
        float4 s2 = ((const float4*)cls[2])[idx];
        float4 s3 = ((const float4*)cls[3])[idx];
        ((float4*)(clspart + (size_t)b * NC * DD))[idx] =
            make_float4((s0.x + s1.x) + (s2.x + s3.x), (s0.y + s1.y) + (s2.y + s3.y),
                        (s0.z + s1.z) + (s2.z + s3.z), (s0.w + s1.w) + (s2.w + s3.w));
    }
    if (b == 0 && t == 0) out[0] = 0.f;
}

// Fused loss: blocks 0..31 = classred -> atomicAdd(out, pos_c*SCALE);
// blocks 32..2111 = LDS-free fp8 tile GEMM. acc starts at 0 (no pre-MFMA
// loads); epilogue uses a conservative bound (min acc + min sq_i + min sq_j)
// to gate a never-taken slow path that re-verifies candidates EXACTLY from ys.
__global__ __launch_bounds__(256) void loss_kernel(const uint32_t* __restrict__ a8,
                                                   const uint32_t* __restrict__ b8,
                                                   const float* __restrict__ sq,
                                                   const int* __restrict__ lab,
                                                   const float* __restrict__ clspart,
                                                   const float* __restrict__ ys,
                                                   float* __restrict__ out) {
    int p = blockIdx.x, t = threadIdx.x;

    if (p < NC) {
        // ---- classred for class p: pos_c = n_c*ssq_c - ||S_c||^2 ----
        __shared__ float sp[2][DD];
        __shared__ float redc[4], reds[4], red2[2];
        int col = t & 127, half = t >> 7;
        float S0 = 0.f, S1 = 0.f, S2 = 0.f, S3 = 0.f;
        const float* cp = clspart + (size_t)half * 128 * NC * DD + p * DD + col;
#pragma unroll 8
        for (int pb = 0; pb < 128; pb += 4) {
            S0 += cp[(size_t)(pb + 0) * NC * DD];
            S1 += cp[(size_t)(pb + 1) * NC * DD];
            S2 += cp[(size_t)(pb + 2) * NC * DD];
            S3 += cp[(size_t)(pb + 3) * NC * DD];
        }
        sp[half][col] = (S0 + S1) + (S2 + S3);

        float cnt = 0.f, ssq = 0.f;
        for (int rr = t; rr < NN; rr += 256) {
            if (lab[rr] == p) { cnt += 1.f; ssq += sq[rr]; }
        }
#pragma unroll
        for (int off = 32; off >= 1; off >>= 1) {
            cnt += __shfl_down(cnt, off);
            ssq += __shfl_down(ssq, off);
        }
        if ((t & 63) == 0) { redc[t >> 6] = cnt; reds[t >> 6] = ssq; }
        __syncthreads();

        float s2 = 0.f;
        if (t < DD) { float Sc = sp[0][t] + sp[1][t]; s2 = Sc * Sc; }
#pragma unroll
        for (int off = 32; off >= 1; off >>= 1) s2 += __shfl_down(s2, off);
        if (t < 128 && (t & 63) == 0) red2[t >> 6] = s2;
        __syncthreads();
        if (t == 0) {
            float c = redc[0] + redc[1] + redc[2] + redc[3];
            float s = reds[0] + reds[1] + reds[2] + reds[3];
            atomicAdd(out, (c * s - (red2[0] + red2[1])) * SCALE);
        }
        return;
    }

    // ---- tile GEMM ----
    int pt = p - NC;
    int q = (NBLK - 1) - pt;
    int r = (int)((sqrtf(8.0f * (float)q + 1.0f) - 1.0f) * 0.5f);
    while (r * (r + 1) / 2 > q) --r;
    while ((r + 1) * (r + 2) / 2 <= q) ++r;
    int bi = (NB - 1) - r;
    int bj = (NB - 1) - (q - r * (r + 1) / 2);
    int i0 = bi * 128, j0 = bj * 128;

    int wave = t >> 6, lane = t & 63;
    int wm = wave >> 1, wn = wave & 1;
    int lr = lane & 15, lg = lane >> 4;

    f32x4 acc[4][4];
#pragma unroll
    for (int m = 0; m < 4; ++m)
#pragma unroll
        for (int n = 0; n < 4; ++n) acc[m][n] = (f32x4){0.f, 0.f, 0.f, 0.f};

    const char* pa = (const char*)a8 + ((size_t)(i0 >> 4) + wm * 4) * 2048 + lg * 128 + lr * 8;
    const char* pbp = (const char*)b8 + ((size_t)(j0 >> 4) + wn * 4) * 2048 + lg * 128 + lr * 8;

#pragma unroll
    for (int ks = 0; ks < 4; ++ks) {
        long af[4], bf[4];
#pragma unroll
        for (int m = 0; m < 4; ++m) af[m] = *(const long*)(pa + m * 2048 + ks * 512);
#pragma unroll
        for (int n = 0; n < 4; ++n) bf[n] = *(const long*)(pbp + n * 2048 + ks * 512);
#pragma unroll
        for (int m = 0; m < 4; ++m)
#pragma unroll
            for (int n = 0; n < 4; ++n)
                acc[m][n] = __builtin_amdgcn_mfma_f32_16x16x32_fp8_fp8(af[m], bf[n], acc[m][n], 0, 0, 0);
    }

    // acc[m][n][q] == -2*dot_fp8(i,j); d2 = acc + sq_i + sq_j.
    // Conservative tile bound: min(acc) + min_tile(sq_i) + min_tile(sq_j).
    float msi = fminf(sq[i0 + lane * 2], sq[i0 + lane * 2 + 1]);
    float msj = fminf(sq[j0 + lane * 2], sq[j0 + lane * 2 + 1]);
#pragma unroll
    for (int off = 32; off >= 1; off >>= 1) {
        msi = fminf(msi, __shfl_xor(msi, off));
        msj = fminf(msj, __shfl_xor(msj, off));
    }
    float mn = acc[0][0][0];
#pragma unroll
    for (int m = 0; m < 4; ++m)
#pragma unroll
        for (int n = 0; n < 4; ++n)
#pragma unroll
            for (int qq = 0; qq < 4; ++qq) mn = fminf(mn, acc[m][n][qq]);

    if (__any(mn + msi + msj < 20.0f)) {
        // Slow path (never taken for this data): exact re-verification from ys.
        float ns = 0.f;
#pragma unroll
        for (int m = 0; m < 4; ++m)
#pragma unroll
            for (int n = 0; n < 4; ++n)
#pragma unroll
                for (int qq = 0; qq < 4; ++qq) {
                    int i = i0 + wm * 64 + m * 16 + lg * 4 + qq;
                    int j = j0 + wn * 64 + n * 16 + lr;
                    float d2a = acc[m][n][qq] + sq[i] + sq[j];
                    if (d2a < 20.0f && i < j && lab[i] != lab[j]) {
                        float d2e = 0.f;
                        for (int d = 0; d < DD; ++d) {
                            float df = ys[(size_t)i * DD + d] - ys[(size_t)j * DD + d];
                            d2e += df * df;
                        }
                        if (d2e < 1.0f) { float e = 1.0f - sqrtf(d2e); ns += e * e; }
                    }
                }
        if (ns != 0.f) atomicAdd(out, ns * SCALE);
    }
}

extern "C" void kernel_launch(void* const* d_in, const int* in_sizes, int n_in,
                              void* d_out, int out_size, void* d_ws, size_t ws_size,
                              hipStream_t stream) {
    const float* ys = (const float*)d_in[0];
    const int* lab = (const int*)d_in[1];
    float* out = (float*)d_out;

    char* w = (char*)d_ws;
    uint32_t* a8    = (uint32_t*)(w);                 // 1 MB (-2y fp8, frag-major)
    uint32_t* b8    = (uint32_t*)(w + 1048576);       // 1 MB (y fp8)
    float* sq       = (float*)(w + 2097152);          // 32 KB
    float* clspart  = (float*)(w + 2129920);          // 4 MB

    prep_kernel<<<NPB, 256, 0, stream>>>(ys, lab, a8, b8, sq, clspart, out);
    loss_kernel<<<TOTBLK, 256, 0, stream>>>(a8, b8, sq, lab, clspart, ys, out);
}